// Round 12
// baseline (117.481 us; speedup 1.0000x reference)
//
#include <hip/hip_runtime.h>

typedef __attribute__((ext_vector_type(8))) short bf16x8;
typedef __attribute__((ext_vector_type(4))) float f32x4;

#define SL 512
#define SLP 544               // padded seq rows per batch (rows 512..543 zero)
#define LN 100
#define MT 128                // t-rows per block
#define CH_USH 8192           // global filter chunk: 128 rows * 64 ush
#define NCHTOT 96             // 24 + 32 + 40 chunks
#define B_LDS_USH (112 * 64)  // 7168 ush = 14336 B per B buffer (2 bufs)
#define A_USH (136 * 64)      // 8704 ush = 17408 B (single buffer -> 46 KB total)
#define EMB_OFF ((size_t)NCHTOT * CH_USH * 2)
#define EMB_BYTES ((size_t)64 * SLP * 512 * 2)
#define POOL_OFF (EMB_OFF + EMB_BYTES)

__device__ inline unsigned short f2bf(float x) {
    unsigned int u = __float_as_uint(x);
    u = u + 0x7FFFu + ((u >> 16) & 1u);   // RNE
    return (unsigned short)(u >> 16);
}
__device__ inline unsigned int pack2(float a, float b) {
    return (unsigned int)f2bf(a) | ((unsigned int)f2bf(b) << 16);
}
__device__ __forceinline__ void gload16(void* lds, const void* g) {
    __builtin_amdgcn_global_load_lds(
        (const __attribute__((address_space(1))) unsigned int*)g,
        (__attribute__((address_space(3))) unsigned int*)lds, 16, 0, 0);
}

// ---- fused prep: blocks [0,384) convert filters (+ zero pooled);
//      blocks [384,..) gather+convert embedding ------------------------------
__global__ __launch_bounds__(256)
void prep(const float* __restrict__ f3, const float* __restrict__ f4,
          const float* __restrict__ f5, const int* __restrict__ words,
          const float* __restrict__ emb, unsigned short* __restrict__ fbf,
          unsigned short* __restrict__ embseq, unsigned int* __restrict__ pooled) {
    if (blockIdx.x < 384) {
        // filters f32 -> bf16 chunks [96][128 rows][64 ush], source-side XOR
        // swizzle (store unit up holds logical u = up ^ (l&7))
        int id = blockIdx.x * 256 + threadIdx.x;      // < 96*1024
        if (id < 64 * 300) pooled[id] = 0u;
        int c  = id >> 10, rr = id & 1023;
        int l  = rr >> 3, up = rr & 7;
        int wz, cc;
        if (c < 24)      { wz = 0; cc = c; }
        else if (c < 56) { wz = 1; cc = c - 24; }
        else             { wz = 2; cc = c - 56; }
        int w  = 3 + wz;
        int dc = cc / w, p = cc - dc * w;
        int u  = up ^ (l & 7);
        uint4 ov = make_uint4(0u, 0u, 0u, 0u);
        if (l < LN) {
            const float* src = (wz == 0) ? f3 : (wz == 1 ? f4 : f5);
            const float4* s4 = (const float4*)(src + (size_t)l * (w * 512) + p * 512 + dc * 64 + u * 8);
            float4 lo = s4[0], hi = s4[1];
            ov.x = pack2(lo.x, lo.y); ov.y = pack2(lo.z, lo.w);
            ov.z = pack2(hi.x, hi.y); ov.w = pack2(hi.z, hi.w);
        }
        *(uint4*)(fbf + (size_t)c * CH_USH + l * 64 + up * 8) = ov;
    } else {
        // embseq[b][t][d] bf16, zero rows for t >= SL
        int r    = (blockIdx.x - 384) * 4 + (threadIdx.x >> 6);   // < 64*SLP
        int lane = threadIdx.x & 63;
        int b    = r / SLP, t = r - b * SLP;
        uint4 ov = make_uint4(0u, 0u, 0u, 0u);
        if (t < SL) {
            int widx = words[b * SL + t];
            const float4* s4 = (const float4*)(emb + (size_t)widx * 512 + lane * 8);
            float4 lo = s4[0], hi = s4[1];
            ov.x = pack2(lo.x, lo.y); ov.y = pack2(lo.z, lo.w);
            ov.z = pack2(hi.x, hi.y); ov.w = pack2(hi.z, hi.w);
        }
        *(uint4*)(embseq + (size_t)r * 512 + lane * 8) = ov;
    }
}

// ---- MFMA block for one (kk pair), templated n-tile count (static acc idx) --
template<int NT>
__device__ __forceinline__ void mfma_np(const char* __restrict__ Ab,
                                        const char* __restrict__ Bb,
                                        int wm, int wn, int lane, int p,
                                        f32x4 (&acc)[4][4]) {
    #pragma unroll
    for (int kk = 0; kk < 2; ++kk) {
        const int kb2 = (kk << 6) + ((lane >> 4) << 4);
        bf16x8 a[4];
        #pragma unroll
        for (int mi = 0; mi < 4; ++mi) {
            const int ar = wm * 64 + mi * 16 + (lane & 15) + p;
            a[mi] = *(const bf16x8*)(Ab + ar * 128 + (kb2 ^ ((ar & 7) << 4)));
        }
        #pragma unroll
        for (int i = 0; i < NT; ++i) {
            const int l = wn * 64 + i * 16 + (lane & 15);
            bf16x8 bf = *(const bf16x8*)(Bb + l * 128 + (kb2 ^ ((l & 7) << 4)));
            #pragma unroll
            for (int mi = 0; mi < 4; ++mi)
                acc[mi][i] = __builtin_amdgcn_mfma_f32_16x16x32_bf16(
                    a[mi], bf, acc[mi][i], 0, 0, 0);
        }
    }
}

template<int NT>
__device__ __forceinline__ void epilogue_np(f32x4 (&acc)[4][4], int wn, int lane,
                                            const float* __restrict__ bias,
                                            unsigned int* __restrict__ prow) {
    #pragma unroll
    for (int i = 0; i < NT; ++i) {
        int l = wn * 64 + i * 16 + (lane & 15);
        float bv = (l < LN) ? bias[l] : 0.0f;
        float m = 0.0f;   // relu floor
        #pragma unroll
        for (int mi = 0; mi < 4; ++mi)
            #pragma unroll
            for (int j = 0; j < 4; ++j)
                m = fmaxf(m, acc[mi][i][j] + bv);
        m = fmaxf(m, __shfl_xor(m, 16));
        m = fmaxf(m, __shfl_xor(m, 32));
        if (lane < 16 && l < LN)
            atomicMax(&prow[l], __float_as_uint(m));
    }
}

// ---- fused conv + bias + relu + max-pool: 2M x 2N wave split ----------------
template<int W>
__device__ __forceinline__ void conv_body(
    unsigned short* __restrict__ As,            // 1 * A_USH
    unsigned short* __restrict__ Bs,            // 2 * B_LDS_USH
    const unsigned short* __restrict__ embB,
    const unsigned short* __restrict__ fchunks,
    const float* __restrict__ bias,
    unsigned int* __restrict__ prow)
{
    const int tid = threadIdx.x, lane = tid & 63;
    const int wv = tid >> 6, wm = wv & 1, wn = wv >> 1;

    auto stageB = [&](int chunk, int buf) {     // 896 units
        const unsigned short* g = fchunks + (size_t)chunk * CH_USH;
        unsigned short* dst = Bs + buf * B_LDS_USH;
        #pragma unroll
        for (int j = 0; j < 4; ++j) {
            int k = tid + j * 256;
            if (k < 896) gload16(dst + ((k >> 6) << 9), g + k * 8);
        }
    };
    auto stageA = [&](int dcv) {                // 1088 units
        #pragma unroll
        for (int j = 0; j < 5; ++j) {
            int k = tid + j * 256;
            if (k < 1088) {
                int row = k >> 3, u = (k & 7) ^ (row & 7);
                gload16(As + ((k >> 6) << 9),
                        embB + (size_t)row * 512 + dcv * 64 + u * 8);
            }
        }
    };

    stageA(0);
    stageB(0, 0);
    __syncthreads();

    f32x4 acc[4][4] = {};

    #pragma unroll 1
    for (int dc = 0; dc < 8; ++dc) {
        #pragma unroll
        for (int p = 0; p < W; ++p) {
            const int s = dc * W + p;
            if (s + 1 < 8 * W) stageB(s + 1, (s + 1) & 1);   // issue before compute

            const char* Ab = (const char*)As;
            const char* Bb = (const char*)(Bs + (s & 1) * B_LDS_USH);
            if (wn == 0) mfma_np<4>(Ab, Bb, wm, wn, lane, p, acc);
            else         mfma_np<3>(Ab, Bb, wm, wn, lane, p, acc);

            __syncthreads();               // seals A(dc)+B(s) reads, lands B(s+1)
            if (p == W - 1 && dc < 7) {    // A single buffer: refill after seal
                stageA(dc + 1);
                __syncthreads();           // drain A loads (hidden by the other
            }                              // 2 resident blocks)
        }
    }

    if (wn == 0) epilogue_np<4>(acc, wn, lane, bias, prow);
    else         epilogue_np<3>(acc, wn, lane, bias, prow);
}

__global__ __launch_bounds__(256, 3)
void conv_pool(const unsigned short* __restrict__ embseq,
               const unsigned short* __restrict__ fbf,
               const float* __restrict__ b3, const float* __restrict__ b4,
               const float* __restrict__ b5, unsigned int* __restrict__ pooled) {
    __shared__ __align__(16) unsigned short As[A_USH];           // 17.4 KB
    __shared__ __align__(16) unsigned short Bs[2 * B_LDS_USH];   // 28.7 KB
    const int wz = blockIdx.z, b = blockIdx.y, t0 = blockIdx.x * MT;
    const unsigned short* embB = embseq + ((size_t)(b * SLP + t0)) * 512;
    unsigned int* prow = pooled + (size_t)b * 300 + wz * 100;
    if (wz == 0)      conv_body<3>(As, Bs, embB, fbf,                b3, prow);
    else if (wz == 1) conv_body<4>(As, Bs, embB, fbf + 24u * CH_USH, b4, prow);
    else              conv_body<5>(As, Bs, embB, fbf + 56u * CH_USH, b5, prow);
}

// ---- final [64,300] x [300,10], wave-parallel dots --------------------------
__global__ __launch_bounds__(256)
void out_gemm(const unsigned int* __restrict__ pooled,
              const float* __restrict__ W, float* __restrict__ out) {
    int b = blockIdx.x;
    __shared__ float pshared[300];
    int tid = threadIdx.x;
    for (int i = tid; i < 300; i += 256)
        pshared[i] = __uint_as_float(pooled[b * 300 + i]);
    __syncthreads();
    int wv = tid >> 6, lane = tid & 63;
    for (int o = wv; o < 10; o += 4) {
        float s = 0.f;
        #pragma unroll
        for (int j = 0; j < 5; ++j) {
            int c = lane + j * 64;
            if (c < 300) s += pshared[c] * W[c * 10 + o];
        }
        #pragma unroll
        for (int off = 32; off; off >>= 1) s += __shfl_down(s, off);
        if (lane == 0) out[b * 10 + o] = s;
    }
}

extern "C" void kernel_launch(void* const* d_in, const int* in_sizes, int n_in,
                              void* d_out, int out_size, void* d_ws, size_t ws_size,
                              hipStream_t stream) {
    const int*   words = (const int*)d_in[0];
    const float* Emb   = (const float*)d_in[1];
    const float* outW  = (const float*)d_in[2];
    const float* f3    = (const float*)d_in[3];
    const float* b3    = (const float*)d_in[4];
    const float* f4    = (const float*)d_in[5];
    const float* b4    = (const float*)d_in[6];
    const float* f5    = (const float*)d_in[7];
    const float* b5    = (const float*)d_in[8];
    float* out = (float*)d_out;

    unsigned short* fbf    = (unsigned short*)d_ws;
    unsigned short* embseq = (unsigned short*)((char*)d_ws + EMB_OFF);
    unsigned int*   pooled = (unsigned int*)((char*)d_ws + POOL_OFF);

    prep<<<384 + (64 * SLP) / 4, 256, 0, stream>>>(f3, f4, f5, words, Emb,
                                                   fbf, embseq, pooled);
    conv_pool<<<dim3(SL / MT, 64, 3), 256, 0, stream>>>(embseq, fbf, b3, b4, b5, pooled);
    out_gemm<<<64, 256, 0, stream>>>(pooled, outW, out);
}

// Round 13
// 74.584 us; speedup vs baseline: 1.5752x; 1.5752x over previous
//
#include <hip/hip_runtime.h>

typedef __attribute__((ext_vector_type(8))) short bf16x8;
typedef __attribute__((ext_vector_type(4))) float f32x4;

#define SL 512
#define SLP 544               // padded seq rows per batch (rows 512..543 zero)
#define LN 100
#define MT 128                // t-rows per block
#define CH_USH 8192           // global filter chunk: 128 rows * 64 ush
#define NCHTOT 96             // 24 + 32 + 40 chunks
#define B_LDS_USH (128 * 64)  // 8192 ush = 16 KB per B buffer (2 bufs)
#define A_USH (136 * 64)      // 8704 ush = 17.4 KB (single buffer -> 50.2 KB total)
#define EMB_OFF ((size_t)NCHTOT * CH_USH * 2)
#define EMB_BYTES ((size_t)64 * SLP * 512 * 2)
#define POOL_OFF (EMB_OFF + EMB_BYTES)

__device__ inline unsigned short f2bf(float x) {
    unsigned int u = __float_as_uint(x);
    u = u + 0x7FFFu + ((u >> 16) & 1u);   // RNE
    return (unsigned short)(u >> 16);
}
__device__ inline unsigned int pack2(float a, float b) {
    return (unsigned int)f2bf(a) | ((unsigned int)f2bf(b) << 16);
}
__device__ __forceinline__ void gload16(void* lds, const void* g) {
    __builtin_amdgcn_global_load_lds(
        (const __attribute__((address_space(1))) unsigned int*)g,
        (__attribute__((address_space(3))) unsigned int*)lds, 16, 0, 0);
}

// ---- fused prep: blocks [0,384) convert filters (+ zero pooled);
//      blocks [384,..) gather+convert embedding ------------------------------
__global__ __launch_bounds__(256)
void prep(const float* __restrict__ f3, const float* __restrict__ f4,
          const float* __restrict__ f5, const int* __restrict__ words,
          const float* __restrict__ emb, unsigned short* __restrict__ fbf,
          unsigned short* __restrict__ embseq, unsigned int* __restrict__ pooled) {
    if (blockIdx.x < 384) {
        // filters f32 -> bf16 chunks [96][128 rows][64 ush], source-side XOR
        // swizzle (store unit up holds logical u = up ^ (l&7))
        int id = blockIdx.x * 256 + threadIdx.x;      // < 96*1024
        if (id < 64 * 300) pooled[id] = 0u;
        int c  = id >> 10, rr = id & 1023;
        int l  = rr >> 3, up = rr & 7;
        int wz, cc;
        if (c < 24)      { wz = 0; cc = c; }
        else if (c < 56) { wz = 1; cc = c - 24; }
        else             { wz = 2; cc = c - 56; }
        int w  = 3 + wz;
        int dc = cc / w, p = cc - dc * w;
        int u  = up ^ (l & 7);
        uint4 ov = make_uint4(0u, 0u, 0u, 0u);
        if (l < LN) {
            const float* src = (wz == 0) ? f3 : (wz == 1 ? f4 : f5);
            const float4* s4 = (const float4*)(src + (size_t)l * (w * 512) + p * 512 + dc * 64 + u * 8);
            float4 lo = s4[0], hi = s4[1];
            ov.x = pack2(lo.x, lo.y); ov.y = pack2(lo.z, lo.w);
            ov.z = pack2(hi.x, hi.y); ov.w = pack2(hi.z, hi.w);
        }
        *(uint4*)(fbf + (size_t)c * CH_USH + l * 64 + up * 8) = ov;
    } else {
        // embseq[b][t][d] bf16, zero rows for t >= SL
        int r    = (blockIdx.x - 384) * 4 + (threadIdx.x >> 6);   // < 64*SLP
        int lane = threadIdx.x & 63;
        int b    = r / SLP, t = r - b * SLP;
        uint4 ov = make_uint4(0u, 0u, 0u, 0u);
        if (t < SL) {
            int widx = words[b * SL + t];
            const float4* s4 = (const float4*)(emb + (size_t)widx * 512 + lane * 8);
            float4 lo = s4[0], hi = s4[1];
            ov.x = pack2(lo.x, lo.y); ov.y = pack2(lo.z, lo.w);
            ov.z = pack2(hi.x, hi.y); ov.w = pack2(hi.z, hi.w);
        }
        *(uint4*)(embseq + (size_t)r * 512 + lane * 8) = ov;
    }
}

// ---- fused conv + bias + relu + max-pool: uniform 2M x 2N wave split --------
// N padded to 128 (8 n-tiles, 4 per wave); straight-line, static acc indexing.
template<int W>
__device__ __forceinline__ void conv_body(
    unsigned short* __restrict__ As,            // 1 * A_USH
    unsigned short* __restrict__ Bs,            // 2 * B_LDS_USH
    const unsigned short* __restrict__ embB,
    const unsigned short* __restrict__ fchunks,
    const float* __restrict__ bias,
    unsigned int* __restrict__ prow)
{
    const int tid = threadIdx.x, lane = tid & 63;
    const int wv = tid >> 6, wm = wv & 1, wn = wv >> 1;

    auto stageB = [&](int chunk, int buf) {     // 1024 units, 4/thread exact
        const unsigned short* g = fchunks + (size_t)chunk * CH_USH;
        unsigned short* dst = Bs + buf * B_LDS_USH;
        #pragma unroll
        for (int j = 0; j < 4; ++j) {
            int k = tid + j * 256;
            gload16(dst + ((k >> 6) << 9), g + k * 8);
        }
    };
    auto stageA = [&](int dcv) {                // 1088 units
        #pragma unroll
        for (int j = 0; j < 5; ++j) {
            int k = tid + j * 256;
            if (k < 1088) {
                int row = k >> 3, u = (k & 7) ^ (row & 7);
                gload16(As + ((k >> 6) << 9),
                        embB + (size_t)row * 512 + dcv * 64 + u * 8);
            }
        }
    };

    stageA(0);
    stageB(0, 0);
    __syncthreads();

    f32x4 acc[4][4] = {};

    #pragma unroll 1
    for (int dc = 0; dc < 8; ++dc) {
        #pragma unroll
        for (int p = 0; p < W; ++p) {
            const int s = dc * W + p;
            if (s + 1 < 8 * W) stageB(s + 1, (s + 1) & 1);   // issue before compute

            const char* Ab = (const char*)As;
            const char* Bb = (const char*)(Bs + (s & 1) * B_LDS_USH);
            #pragma unroll
            for (int kk = 0; kk < 2; ++kk) {
                const int kb2 = (kk << 6) + ((lane >> 4) << 4);
                bf16x8 a[4];
                #pragma unroll
                for (int mi = 0; mi < 4; ++mi) {
                    const int ar = wm * 64 + mi * 16 + (lane & 15) + p;
                    a[mi] = *(const bf16x8*)(Ab + ar * 128 + (kb2 ^ ((ar & 7) << 4)));
                }
                #pragma unroll
                for (int n = 0; n < 4; ++n) {
                    const int l = wn * 64 + (n << 4) + (lane & 15);
                    bf16x8 bf = *(const bf16x8*)(Bb + l * 128 + (kb2 ^ ((l & 7) << 4)));
                    #pragma unroll
                    for (int mi = 0; mi < 4; ++mi)
                        acc[mi][n] = __builtin_amdgcn_mfma_f32_16x16x32_bf16(
                            a[mi], bf, acc[mi][n], 0, 0, 0);
                }
            }

            __syncthreads();               // seals A(dc)+B(s) reads, lands B(s+1)
            if (p == W - 1 && dc < 7) {    // A single buffer: refill after seal
                stageA(dc + 1);
                __syncthreads();           // drain A loads (hidden by the other
            }                              // 2 resident blocks)
        }
    }

    // epilogue: bias + relu + max over wave's 64 t rows, atomicMax merge
    #pragma unroll
    for (int n = 0; n < 4; ++n) {
        int l = wn * 64 + (n << 4) + (lane & 15);
        float bv = (l < LN) ? bias[l] : 0.0f;
        float m = 0.0f;   // relu floor
        #pragma unroll
        for (int mi = 0; mi < 4; ++mi)
            #pragma unroll
            for (int j = 0; j < 4; ++j)
                m = fmaxf(m, acc[mi][n][j] + bv);
        m = fmaxf(m, __shfl_xor(m, 16));
        m = fmaxf(m, __shfl_xor(m, 32));
        if (lane < 16 && l < LN)
            atomicMax(&prow[l], __float_as_uint(m));
    }
}

__global__ __launch_bounds__(256, 3)
void conv_pool(const unsigned short* __restrict__ embseq,
               const unsigned short* __restrict__ fbf,
               const float* __restrict__ b3, const float* __restrict__ b4,
               const float* __restrict__ b5, unsigned int* __restrict__ pooled) {
    __shared__ __align__(16) unsigned short As[A_USH];           // 17.4 KB
    __shared__ __align__(16) unsigned short Bs[2 * B_LDS_USH];   // 32.8 KB
    const int wz = blockIdx.y, b = blockIdx.z, t0 = blockIdx.x * MT;
    const unsigned short* embB = embseq + ((size_t)(b * SLP + t0)) * 512;
    unsigned int* prow = pooled + (size_t)b * 300 + wz * 100;
    if (wz == 0)      conv_body<3>(As, Bs, embB, fbf,                b3, prow);
    else if (wz == 1) conv_body<4>(As, Bs, embB, fbf + 24u * CH_USH, b4, prow);
    else              conv_body<5>(As, Bs, embB, fbf + 56u * CH_USH, b5, prow);
}

// ---- final [64,300] x [300,10], wave-parallel dots --------------------------
__global__ __launch_bounds__(256)
void out_gemm(const unsigned int* __restrict__ pooled,
              const float* __restrict__ W, float* __restrict__ out) {
    int b = blockIdx.x;
    __shared__ float pshared[300];
    int tid = threadIdx.x;
    for (int i = tid; i < 300; i += 256)
        pshared[i] = __uint_as_float(pooled[b * 300 + i]);
    __syncthreads();
    int wv = tid >> 6, lane = tid & 63;
    for (int o = wv; o < 10; o += 4) {
        float s = 0.f;
        #pragma unroll
        for (int j = 0; j < 5; ++j) {
            int c = lane + j * 64;
            if (c < 300) s += pshared[c] * W[c * 10 + o];
        }
        #pragma unroll
        for (int off = 32; off; off >>= 1) s += __shfl_down(s, off);
        if (lane == 0) out[b * 10 + o] = s;
    }
}

extern "C" void kernel_launch(void* const* d_in, const int* in_sizes, int n_in,
                              void* d_out, int out_size, void* d_ws, size_t ws_size,
                              hipStream_t stream) {
    const int*   words = (const int*)d_in[0];
    const float* Emb   = (const float*)d_in[1];
    const float* outW  = (const float*)d_in[2];
    const float* f3    = (const float*)d_in[3];
    const float* b3    = (const float*)d_in[4];
    const float* f4    = (const float*)d_in[5];
    const float* b4    = (const float*)d_in[6];
    const float* f5    = (const float*)d_in[7];
    const float* b5    = (const float*)d_in[8];
    float* out = (float*)d_out;

    unsigned short* fbf    = (unsigned short*)d_ws;
    unsigned short* embseq = (unsigned short*)((char*)d_ws + EMB_OFF);
    unsigned int*   pooled = (unsigned int*)((char*)d_ws + POOL_OFF);

    prep<<<384 + (64 * SLP) / 4, 256, 0, stream>>>(f3, f4, f5, words, Emb,
                                                   fbf, embseq, pooled);
    conv_pool<<<dim3(SL / MT, 3, 64), 256, 0, stream>>>(embseq, fbf, b3, b4, b5, pooled);
    out_gemm<<<64, 256, 0, stream>>>(pooled, outW, out);
}